// Round 5
// baseline (72.622 us; speedup 1.0000x reference)
//
#include <hip/hip_runtime.h>
#include <hip/hip_bf16.h>
#include <math.h>

#define Bq 8
#define Nq 1024
#define Dq 256
#define Hq 8
#define HDq 32
#define LOG2E 1.44269504f

typedef __attribute__((ext_vector_type(8)))  short short8v;
typedef __attribute__((ext_vector_type(4)))  float f32x4;
typedef __attribute__((ext_vector_type(16))) float f32x16;

// ---------------------------------------------------------------------------
// Kernel 1 (fused role-split):
//  blocks [0,512):   bf16 MFMA GEMM h = x*W^T + b, epilogue -> h_bT (bf16,
//                    transposed) + s_i2/s_j2 (prescaled by LOG2E)
//  blocks [512,2560): pack adj rows into bitmasks adjw[b][i][0:32)
// ---------------------------------------------------------------------------
__global__ __launch_bounds__(256) void gemm_pack(const float* __restrict__ x,
                                                 const float* __restrict__ W,
                                                 const float* __restrict__ Wb,
                                                 const float* __restrict__ a,
                                                 const int* __restrict__ adj,
                                                 __hip_bfloat16* __restrict__ h_bT,
                                                 float* __restrict__ s_i2,
                                                 float* __restrict__ s_j2,
                                                 unsigned* __restrict__ adjw) {
    __shared__ __hip_bfloat16 xs[64][68];
    __shared__ __hip_bfloat16 wsm[64][68];
    __shared__ __hip_bfloat16 ht[64][72];
    const int t = threadIdx.x;
    const int lane = t & 63, wv = t >> 6;

    if (blockIdx.x >= 512) {
        const size_t row = ((size_t)blockIdx.x - 512) * 4 + wv;   // 0..8191
        const int* ar = adj + row * Nq;
        unsigned* wr = adjw + row * 32;
        #pragma unroll
        for (int it = 0; it < 16; ++it) {
            int v = ar[it * 64 + lane];
            unsigned long long mask = __ballot(v != 0);
            if (lane == 0) {
                wr[it * 2 + 0] = (unsigned)mask;
                wr[it * 2 + 1] = (unsigned)(mask >> 32);
            }
        }
        return;
    }

    const int m0 = (blockIdx.x & 127) * 64;
    const int o0 = (blockIdx.x >> 7) * 64;
    const int lo = lane & 31, hi = lane >> 5;
    const int mw = (wv & 1) * 32, ow = (wv >> 1) * 32;
    const int b = m0 >> 10;
    f32x16 acc = 0.f;

    for (int k0 = 0; k0 < 256; k0 += 64) {
        __syncthreads();
        #pragma unroll
        for (int it = 0; it < 4; ++it) {
            int f4  = t + it * 256;
            int row = f4 >> 4;
            int c4  = (f4 & 15) * 4;
            float4 xv = *(const float4*)(x + (size_t)(m0 + row) * 256 + k0 + c4);
            float4 wv2 = *(const float4*)(W + (size_t)(o0 + row) * 256 + k0 + c4);
            union { ushort4 u; __bf16 e[4]; } xb, wb;
            xb.e[0] = (__bf16)xv.x; xb.e[1] = (__bf16)xv.y;
            xb.e[2] = (__bf16)xv.z; xb.e[3] = (__bf16)xv.w;
            wb.e[0] = (__bf16)wv2.x; wb.e[1] = (__bf16)wv2.y;
            wb.e[2] = (__bf16)wv2.z; wb.e[3] = (__bf16)wv2.w;
            *(ushort4*)(&xs[row][c4])  = xb.u;
            *(ushort4*)(&wsm[row][c4]) = wb.u;
        }
        __syncthreads();
        #pragma unroll
        for (int kk = 0; kk < 4; ++kk) {
            short8v av = *(const short8v*)(&xs[mw + lo][kk * 16 + hi * 8]);
            short8v bv = *(const short8v*)(&wsm[ow + lo][kk * 16 + hi * 8]);
            acc = __builtin_amdgcn_mfma_f32_32x32x16_bf16(av, bv, acc, 0, 0, 0);
        }
    }

    __syncthreads();
    const float bias = Wb[o0 + ow + lo];
    #pragma unroll
    for (int rg = 0; rg < 16; ++rg) {
        int row = (rg & 3) + 8 * (rg >> 2) + 4 * hi;
        float v = acc[rg] + bias;
        ht[ow + lo][mw + row] = (__hip_bfloat16)v;
    }
    __syncthreads();

    #pragma unroll
    for (int it = 0; it < 2; ++it) {
        int s8 = t + it * 256;
        int ol = s8 >> 3;
        int n8 = (s8 & 7) * 8;
        short8v v = *(const short8v*)(&ht[ol][n8]);
        int o = o0 + ol;
        size_t drow = (size_t)((b * Hq + (o >> 5)) * HDq + (o & 31));
        *(short8v*)((unsigned short*)h_bT + drow * Nq + (m0 & 1023) + n8) = v;
    }
    if (t < 128) {
        int hd = t >> 6, nl = t & 63;
        const float* ab = a + b * 64;
        float si = 0.f, sj = 0.f;
        #pragma unroll
        for (int d = 0; d < 32; ++d) {
            float hv = (float)ht[hd * 32 + d][nl];
            si += hv * ab[d];
            sj += hv * ab[32 + d];
        }
        int bh = b * Hq + (o0 >> 5) + hd;
        int n  = (m0 & 1023) + nl;
        s_i2[(size_t)bh * Nq + n] = si * LOG2E;
        s_j2[(size_t)bh * Nq + n] = sj * LOG2E;
    }
}

// ---------------------------------------------------------------------------
// Kernel 2: attention v5 — NO LDS, NO BARRIERS, 1 wave per block.
// Each lane's MFMA B-fragment is a fixed h_bT row (d = lane&15 [+16]); read
// it directly from global (L1/L2-served; 4 jg-groups hit the same 64B line
// of 16 rows -> full line use). s_j float4s likewise (broadcast across the
// 16 lanes of a jg group -> coalesced to 4 lines). XCD-bijective block
// swizzle keeps each bh's 64KB working set inside one XCD's L2 and gives
// consecutive blocks on a CU the same bh (L1 reuse).
// Single-pass softmax, no max shift (p = exp2(lrelu(si+sj)) <= 2^~36, safe).
// Writes UNNORMALIZED acc + per-row l (divide folded into LN).
// ---------------------------------------------------------------------------
__global__ __launch_bounds__(64) void attn_v5(const __hip_bfloat16* __restrict__ h_bT,
                                              const unsigned* __restrict__ adjw,
                                              const float* __restrict__ s_i2,
                                              const float* __restrict__ s_j2,
                                              float* __restrict__ att_un,
                                              float* __restrict__ lsum_arr) {
    // bijective XCD swizzle: 4096 blocks = 8 XCDs x 512; XCD k gets ids
    // [k*512, (k+1)*512) = bh [k*8, (k+1)*8)
    const int id = ((int)blockIdx.x & 7) * 512 + ((int)blockIdx.x >> 3);
    const int bh = id >> 6;                  // 64 blocks (waves) per bh
    const int b  = bh >> 3, hh = bh & 7;
    const int i0 = (id & 63) * 16;
    const int lane = threadIdx.x;            // 0..63
    const int r16 = lane & 15, jg = lane >> 4;
    const int iG = i0 + r16;
    const unsigned shft = jg * 8;

    const float si = s_i2[(size_t)bh * Nq + iG];
    const unsigned short* hb0 = (const unsigned short*)h_bT + (size_t)bh * HDq * Nq
                              + (size_t)r16 * Nq;
    const float* sjb = s_j2 + (size_t)bh * Nq + jg * 8;
    const unsigned* awb = adjw + ((size_t)b * Nq + iG) * 32;

    f32x4 acc0 = 0.f, acc1 = 0.f;
    float l = 0.f;

    #pragma unroll
    for (int c = 0; c < 4; ++c) {
        const int j0 = c * 256;
        uint4 a0 = *(const uint4*)(awb + c * 8);
        uint4 a1 = *(const uint4*)(awb + c * 8 + 4);
        unsigned aw[8] = {a0.x, a0.y, a0.z, a0.w, a1.x, a1.y, a1.z, a1.w};

        #pragma unroll
        for (int s = 0; s < 8; ++s) {
            const int jb = j0 + s * 32;          // + jg*8 folded into bases
            float4 sv0 = *(const float4*)(sjb + jb);
            float4 sv1 = *(const float4*)(sjb + jb + 4);
            short8v fb0 = *(const short8v*)(hb0 + jb + jg * 8);
            short8v fb1 = *(const short8v*)(hb0 + 16 * Nq + jb + jg * 8);
            float sjv[8] = {sv0.x, sv0.y, sv0.z, sv0.w, sv1.x, sv1.y, sv1.z, sv1.w};
            unsigned wbits = aw[s] >> shft;
            union { short8v v; __bf16 e[8]; } pa;
            float ls = 0.f;
            #pragma unroll
            for (int e = 0; e < 8; ++e) {
                float sc = si + sjv[e];
                sc = fmaxf(sc, 0.2f * sc);                 // lrelu (log2-scaled)
                sc = ((wbits >> e) & 1u) ? sc : -30000.f;  // mask -> exp2 = 0
                float p = exp2f(sc);
                ls += p;
                pa.e[e] = (__bf16)p;
            }
            l += ls;
            acc0 = __builtin_amdgcn_mfma_f32_16x16x32_bf16(pa.v, fb0, acc0, 0, 0, 0);
            acc1 = __builtin_amdgcn_mfma_f32_16x16x32_bf16(pa.v, fb1, acc1, 0, 0, 0);
        }
    }

    // row-sum of l across the 4 jg-groups (row r16 partials in lanes r16+16k)
    l += __shfl_xor(l, 16);
    l += __shfl_xor(l, 32);
    if (lane < 16) lsum_arr[(size_t)bh * Nq + iG] = l;

    // C/D 16x16: col = lane&15, row = (lane>>4)*4 + reg
    #pragma unroll
    for (int rg = 0; rg < 4; ++rg) {
        int row = jg * 4 + rg;
        size_t base = ((size_t)b * Nq + i0 + row) * Dq + hh * HDq;
        att_un[base + r16]      = acc0[rg];
        att_un[base + 16 + r16] = acc1[rg];
    }
}

// ---------------------------------------------------------------------------
// Kernel 3: out = LN(att_un/l + x) * gamma + beta (torch unbiased, /(std+eps))
// ---------------------------------------------------------------------------
__global__ __launch_bounds__(256) void ln_k(const float* __restrict__ att_un,
                                            const float* __restrict__ lsum_arr,
                                            const float* __restrict__ x,
                                            const float* __restrict__ gamma,
                                            const float* __restrict__ beta,
                                            float* __restrict__ out) {
    const int t = threadIdx.x, lane = t & 63, wv = t >> 6;
    const size_t row  = (size_t)blockIdx.x * 4 + wv;
    const int b = (int)(row >> 10), n = (int)(row & 1023);
    const size_t base = row * Dq + lane * 4;
    float4 av = *(const float4*)(att_un + base);
    float4 xv = *(const float4*)(x + base);
    float rl = 1.f / lsum_arr[(size_t)(b * Hq + (lane >> 3)) * Nq + n];
    float o0 = av.x * rl + xv.x, o1 = av.y * rl + xv.y;
    float o2 = av.z * rl + xv.z, o3 = av.w * rl + xv.w;
    float s  = o0 + o1 + o2 + o3;
    float sq = o0 * o0 + o1 * o1 + o2 * o2 + o3 * o3;
    #pragma unroll
    for (int off = 32; off; off >>= 1) {
        s  += __shfl_xor(s, off);
        sq += __shfl_xor(sq, off);
    }
    float mean = s * (1.f / 256.f);
    float var  = (sq - 256.f * mean * mean) * (1.f / 255.f);
    var = fmaxf(var, 0.f);
    float inv = 1.f / (sqrtf(var) + 1e-6f);
    float4 g  = *(const float4*)(gamma + lane * 4);
    float4 bt = *(const float4*)(beta + lane * 4);
    float4 ov;
    ov.x = (o0 - mean) * inv * g.x + bt.x;
    ov.y = (o1 - mean) * inv * g.y + bt.y;
    ov.z = (o2 - mean) * inv * g.z + bt.z;
    ov.w = (o3 - mean) * inv * g.w + bt.w;
    *(float4*)(out + base) = ov;
}

// ---------------------------------------------------------------------------
extern "C" void kernel_launch(void* const* d_in, const int* in_sizes, int n_in,
                              void* d_out, int out_size, void* d_ws, size_t ws_size,
                              hipStream_t stream) {
    const float* x     = (const float*)d_in[0];
    const int*   adj   = (const int*)d_in[1];
    const float* W_w   = (const float*)d_in[2];
    const float* W_b   = (const float*)d_in[3];
    const float* a     = (const float*)d_in[4];
    const float* gamma = (const float*)d_in[5];
    const float* beta  = (const float*)d_in[6];
    float* out = (float*)d_out;

    __hip_bfloat16* h_bT = (__hip_bfloat16*)d_ws;
    float* att_un = (float*)((char*)d_ws + (size_t)Bq * Hq * Nq * HDq * 2);
    float* s_i2   = att_un + (size_t)Bq * Nq * Dq;
    float* s_j2   = s_i2 + (size_t)Bq * Hq * Nq;
    float* lsum   = s_j2 + (size_t)Bq * Hq * Nq;
    unsigned* adjw = (unsigned*)(lsum + (size_t)Bq * Hq * Nq);

    gemm_pack<<<2560, 256, 0, stream>>>(x, W_w, W_b, a, adj, h_bT, s_i2, s_j2, adjw);
    attn_v5<<<4096, 64, 0, stream>>>(h_bT, adjw, s_i2, s_j2, att_un, lsum);
    ln_k<<<2048, 256, 0, stream>>>(att_un, lsum, x, gamma, beta, out);
}